// Round 1
// baseline (13003.297 us; speedup 1.0000x reference)
//
#include <hip/hip_runtime.h>
#include <math.h>

// Problem constants (B,S,IN,H,SS from reference; L==S==128, T=L-1=127 steps)
#define BB   128
#define SEQ  128
#define HH   512
#define G3   1536
#define TT   127
#define OSS  100

// ---------------------------------------------------------------------------
// ws layout (floats):
//   P      [B*S*H]          = 8,388,608   inst_proj = instance_hidden @ Wa^T
//   xsel   [B*128*2]        = 32,768      gathered instance[b, sol[b,l], :]
//   A1     [1536*2]                       Wi1 @ Wr   (input-embedding fold)
//   A2     [1536*2]                       Wi2[:, :H] @ Wr
//   c1     [1536]                         Wi1@br + bi1
//   c2     [1536]                         Wi2[:,:H]@br + bi2
//   h1buf  [2][B*H]                       h1 ring (slot = t&1)
//   h2buf  [2][B*H]                       h2 ring
//   ubuf   [2][B*H]                       u = h1 @ Ua^T ring
//   attbuf [2][B*2][520]                  per (b, s-half): m, z, pad, C[512] @ +8
//   ctxbuf [2][B*H]                       combined context ring
// total = 9,221,120 floats = 36.9 MB  (assumes ws_size >= 37 MB)
// ---------------------------------------------------------------------------

__device__ __forceinline__ float sigm(float x) { return 1.0f / (1.0f + __expf(-x)); }
__device__ __forceinline__ float tanh_(float x) {
  // 1 - 2/(exp(2x)+1); safe at +/-inf of the exp
  float e = __expf(2.0f * x);
  return 1.0f - 2.0f / (e + 1.0f);
}

// ===========================================================================
// K0: prep — P GEMM, A1/A2/c1/c2 fold, xsel gather, zero-init of h(-1) slots
// grid: 2056 x 256
// ===========================================================================
__global__ __launch_bounds__(256)
void prep_kernel(const float* __restrict__ instance, const int* __restrict__ solution,
                 const float* __restrict__ Hst, const float* __restrict__ Wr,
                 const float* __restrict__ br, const float* __restrict__ Wi1,
                 const float* __restrict__ bi1, const float* __restrict__ Wi2,
                 const float* __restrict__ bi2, const float* __restrict__ Wa,
                 float* __restrict__ P, float* __restrict__ xsel,
                 float* __restrict__ A1, float* __restrict__ A2,
                 float* __restrict__ c1, float* __restrict__ c2,
                 float* __restrict__ h1buf, float* __restrict__ h2buf)
{
  const int w = blockIdx.x, t = threadIdx.x;
  if (w < 2048) {
    // P[m,h] = sum_k Hst[m,k] * Wa[h,k];  M=16384 tiled 64, N=512 tiled 64
    const int mb = w >> 3, nb = w & 7;
    const int m0 = mb * 64, h0 = nb * 64;
    const int hl = t & 63, mg = t >> 6;         // mg wave-uniform -> Hst rows broadcast
    const int h = h0 + hl;
    const int mbase = m0 + mg * 16;
    const float4* wa4 = (const float4*)(Wa + (size_t)h * HH);
    float acc[16];
#pragma unroll
    for (int r = 0; r < 16; ++r) acc[r] = 0.f;
    for (int k4 = 0; k4 < HH / 4; ++k4) {
      float4 wv = wa4[k4];
#pragma unroll
      for (int r = 0; r < 16; ++r) {
        float4 hv = ((const float4*)(Hst + (size_t)(mbase + r) * HH))[k4];
        acc[r] += hv.x * wv.x + hv.y * wv.y + hv.z * wv.z + hv.w * wv.w;
      }
    }
#pragma unroll
    for (int r = 0; r < 16; ++r) P[(size_t)(mbase + r) * HH + h] = acc[r];
  } else if (w < 2054) {
    // fold: A1[j] = Wi1[j,:]@Wr, c1[j] = Wi1[j,:]@br + bi1[j]; A2/c2 from Wi2[:, :512]
    const int j = (w - 2048) * 256 + t;
    const float* wi1 = Wi1 + (size_t)j * HH;
    const float* wi2 = Wi2 + (size_t)j * 1024;       // row stride 2H
    float a0 = 0.f, a1 = 0.f, cc1 = 0.f, b0 = 0.f, b1v = 0.f, cc2 = 0.f;
    for (int k = 0; k < HH; ++k) {
      float w1 = wi1[k], w2 = wi2[k];
      float r0 = Wr[k * 2], r1 = Wr[k * 2 + 1], bb = br[k];
      a0 += w1 * r0; a1 += w1 * r1; cc1 += w1 * bb;
      b0 += w2 * r0; b1v += w2 * r1; cc2 += w2 * bb;
    }
    A1[j * 2] = a0; A1[j * 2 + 1] = a1; c1[j] = cc1 + bi1[j];
    A2[j * 2] = b0; A2[j * 2 + 1] = b1v; c2[j] = cc2 + bi2[j];
  } else if (w == 2054) {
    // xsel[b,l,:] = instance[b, solution[b,l], :]
    for (int i = 0; i < 64; ++i) {
      int idx = i * 256 + t;                 // b*128 + l
      int b = idx >> 7;
      int sel = solution[idx];
      xsel[idx * 2]     = instance[((size_t)b * SEQ + sel) * 2];
      xsel[idx * 2 + 1] = instance[((size_t)b * SEQ + sel) * 2 + 1];
    }
  } else {
    // zero h1(-1), h2(-1) = slot 1 of each ring (ws is poisoned 0xAA)
    for (int i = 0; i < 256; ++i) {
      h1buf[65536 + i * 256 + t] = 0.f;
      h2buf[65536 + i * 256 + t] = 0.f;
    }
  }
}

// ===========================================================================
// Step kernel: software-pipelined phases. kernel k runs:
//   A(t=k): h1(t) from h1(t-1)                  WGs [0,128)
//   U(t=k-1): u(t) = h1(t) @ Ua^T               WGs [128,192)
//   B(t=k-2): scores/softmax-half/context-half  WGs [192,448)
//   C'(t=k-3): combine halves -> ctx(t)         WGs [448,464)
//   D(t=k-4): h2(t) from h2(t-1), ctx(t)        WGs [464,720)
// grid: 720 x 256;  k = 0..130
// ===========================================================================
__global__ __launch_bounds__(256)
void step_kernel(int k,
                 const float* __restrict__ Hst, const float* __restrict__ Wh1,
                 const float* __restrict__ bh1, const float* __restrict__ Ua,
                 const float* __restrict__ vvec, const float* __restrict__ Wi2,
                 const float* __restrict__ Wh2, const float* __restrict__ bh2,
                 const float* __restrict__ P, const float* __restrict__ xsel,
                 const float* __restrict__ A1, const float* __restrict__ A2,
                 const float* __restrict__ c1, const float* __restrict__ c2,
                 float* __restrict__ h1buf, float* __restrict__ h2buf,
                 float* __restrict__ ubuf, float* __restrict__ attbuf,
                 float* __restrict__ ctxbuf)
{
  const int w = blockIdx.x, t = threadIdx.x;

  if (w < 128) {
    // ---- A: GRU1 update. WG = (b-group of 32) x (c-block of 16)
    const int tA = k;
    if (tA > 126) return;
    const float* h1p = h1buf + ((tA + 1) & 1) * (BB * HH);
    float* h1n = h1buf + (tA & 1) * (BB * HH);
    const int b = (w >> 5) * 32 + (t & 31);
    const int c0 = (w & 31) * 16 + (t >> 5) * 2;   // this thread: c0, c0+1
    const float4* hv4 = (const float4*)(h1p + b * HH);
    float acc[2][3];
#pragma unroll
    for (int ci = 0; ci < 2; ++ci)
#pragma unroll
      for (int g = 0; g < 3; ++g) acc[ci][g] = 0.f;
    const float4* wrow[2][3];
#pragma unroll
    for (int ci = 0; ci < 2; ++ci)
#pragma unroll
      for (int g = 0; g < 3; ++g)
        wrow[ci][g] = (const float4*)(Wh1 + (size_t)(c0 + ci + g * 512) * HH);
    for (int k4 = 0; k4 < HH / 4; ++k4) {
      float4 h = hv4[k4];
#pragma unroll
      for (int ci = 0; ci < 2; ++ci)
#pragma unroll
        for (int g = 0; g < 3; ++g) {
          float4 wv = wrow[ci][g][k4];
          acc[ci][g] += h.x * wv.x + h.y * wv.y + h.z * wv.z + h.w * wv.w;
        }
    }
    const float x0 = xsel[(b * 128 + tA) * 2], x1 = xsel[(b * 128 + tA) * 2 + 1];
#pragma unroll
    for (int ci = 0; ci < 2; ++ci) {
      int c = c0 + ci;
      float gr = acc[ci][0] + bh1[c];
      float gz = acc[ci][1] + bh1[c + 512];
      float gn = acc[ci][2] + bh1[c + 1024];
      float ir = A1[c * 2] * x0 + A1[c * 2 + 1] * x1 + c1[c];
      float iz = A1[(c + 512) * 2] * x0 + A1[(c + 512) * 2 + 1] * x1 + c1[c + 512];
      float in_ = A1[(c + 1024) * 2] * x0 + A1[(c + 1024) * 2 + 1] * x1 + c1[c + 1024];
      float r = sigm(ir + gr), z = sigm(iz + gz);
      float n = tanh_(in_ + r * gn);
      h1n[b * HH + c] = (1.f - z) * n + z * h1p[b * HH + c];
    }

  } else if (w < 192) {
    // ---- U: u = h1 @ Ua^T. WG = c-block of 8 (all b)
    const int tU = k - 1;
    if (tU < 0 || tU > 126) return;
    const float* h1c = h1buf + (tU & 1) * (BB * HH);
    float* u = ubuf + (tU & 1) * (BB * HH);
    const int c0 = (w - 128) * 8 + (t >> 7) * 4;
    const int b = t & 127;
    const float4* hv4 = (const float4*)(h1c + b * HH);
    float acc[4] = {0.f, 0.f, 0.f, 0.f};
    const float4* ur[4];
#pragma unroll
    for (int q = 0; q < 4; ++q) ur[q] = (const float4*)(Ua + (size_t)(c0 + q) * HH);
    for (int k4 = 0; k4 < HH / 4; ++k4) {
      float4 h = hv4[k4];
#pragma unroll
      for (int q = 0; q < 4; ++q) {
        float4 wv = ur[q][k4];
        acc[q] += h.x * wv.x + h.y * wv.y + h.z * wv.z + h.w * wv.w;
      }
    }
#pragma unroll
    for (int q = 0; q < 4; ++q) u[b * HH + c0 + q] = acc[q];

  } else if (w < 448) {
    // ---- B: additive attention for (b, s-half); writes m, z, C_half
    const int tB = k - 2;
    if (tB < 0 || tB > 126) return;
    const int wb = w - 192, b = wb >> 1, half = wb & 1, s0 = half * 64;
    __shared__ float uS[512], vS[512], scoreS[64], wS[64], mzS[2];
    const float* u = ubuf + (tB & 1) * (BB * HH) + b * HH;
    uS[t] = u[t]; uS[t + 256] = u[t + 256];
    vS[t] = vvec[t]; vS[t + 256] = vvec[t + 256];
    __syncthreads();
    const int wave = t >> 6, lane = t & 63, h0 = lane * 8;
    for (int si = 0; si < 16; ++si) {
      int s = s0 + wave * 16 + si;
      const float* prow = P + (size_t)(b * 128 + s) * HH;
      float4 p0 = *(const float4*)(prow + h0);
      float4 p1 = *(const float4*)(prow + h0 + 4);
      float val = tanh_(p0.x + uS[h0 + 0]) * vS[h0 + 0]
                + tanh_(p0.y + uS[h0 + 1]) * vS[h0 + 1]
                + tanh_(p0.z + uS[h0 + 2]) * vS[h0 + 2]
                + tanh_(p0.w + uS[h0 + 3]) * vS[h0 + 3]
                + tanh_(p1.x + uS[h0 + 4]) * vS[h0 + 4]
                + tanh_(p1.y + uS[h0 + 5]) * vS[h0 + 5]
                + tanh_(p1.z + uS[h0 + 6]) * vS[h0 + 6]
                + tanh_(p1.w + uS[h0 + 7]) * vS[h0 + 7];
#pragma unroll
      for (int off = 32; off; off >>= 1) val += __shfl_xor(val, off);
      if (lane == 0) scoreS[wave * 16 + si] = val;
    }
    __syncthreads();
    if (t < 64) {
      float sc = scoreS[t];
      float m = sc;
#pragma unroll
      for (int off = 32; off; off >>= 1) m = fmaxf(m, __shfl_xor(m, off));
      float e = __expf(sc - m);
      float zz = e;
#pragma unroll
      for (int off = 32; off; off >>= 1) zz += __shfl_xor(zz, off);
      wS[t] = e;
      if (t == 0) { mzS[0] = m; mzS[1] = zz; }
    }
    __syncthreads();
    float* ab = attbuf + ((size_t)(tB & 1) * 256 + b * 2 + half) * 520;
    float a0 = 0.f, a1 = 0.f;
    for (int s = 0; s < 64; ++s) {
      float ww = wS[s];
      const float* hr = Hst + (size_t)(b * 128 + s0 + s) * HH;
      a0 += ww * hr[t];
      a1 += ww * hr[t + 256];
    }
    ab[8 + t] = a0; ab[8 + t + 256] = a1;
    if (t == 0) { ab[0] = mzS[0]; ab[1] = mzS[1]; }

  } else if (w < 464) {
    // ---- C': combine softmax halves -> ctx[b][k]
    const int tC = k - 3;
    if (tC < 0 || tC > 126) return;
    const float* abase = attbuf + (size_t)(tC & 1) * 256 * 520;
    float* ctx = ctxbuf + (tC & 1) * (BB * HH);
    const int base = (w - 448) * 4096;
    for (int i = 0; i < 16; ++i) {
      int idx = base + i * 256 + t;
      int b = idx >> 9, kk = idx & 511;
      const float* a0p = abase + (size_t)(b * 2) * 520;
      const float* a1p = abase + (size_t)(b * 2 + 1) * 520;
      float m0 = a0p[0], z0 = a0p[1], m1 = a1p[0], z1 = a1p[1];
      float M = fmaxf(m0, m1);
      float e0 = __expf(m0 - M), e1 = __expf(m1 - M);
      float iZ = 1.f / (z0 * e0 + z1 * e1);
      ctx[idx] = (e0 * a0p[8 + kk] + e1 * a1p[8 + kk]) * iZ;
    }

  } else {
    // ---- D: GRU2 update. WG = (b-group of 32) x (c-block of 8); 1 c per thread
    const int tD = k - 4;
    if (tD < 0 || tD > 126) return;
    const int wd = w - 464;
    const float* h2p = h2buf + ((tD + 1) & 1) * (BB * HH);
    float* h2n = h2buf + (tD & 1) * (BB * HH);
    const float* ctx = ctxbuf + (tD & 1) * (BB * HH);
    const int b = (wd >> 6) * 32 + (t & 31);
    const int c = (wd & 63) * 8 + (t >> 5);
    const float4* hv4 = (const float4*)(h2p + b * HH);
    const float4* cv4 = (const float4*)(ctx + b * HH);
    float ah[3] = {0.f, 0.f, 0.f}, ai[3] = {0.f, 0.f, 0.f};
    const float4* wh[3];
    const float4* wi[3];
#pragma unroll
    for (int g = 0; g < 3; ++g) {
      int j = c + g * 512;
      wh[g] = (const float4*)(Wh2 + (size_t)j * HH);
      wi[g] = (const float4*)(Wi2 + (size_t)j * 1024 + 512);   // ctx half of Wi2 row
    }
    for (int k4 = 0; k4 < HH / 4; ++k4) {
      float4 h = hv4[k4];
      float4 cv = cv4[k4];
#pragma unroll
      for (int g = 0; g < 3; ++g) {
        float4 wv = wh[g][k4];
        ah[g] += h.x * wv.x + h.y * wv.y + h.z * wv.z + h.w * wv.w;
        float4 wc = wi[g][k4];
        ai[g] += cv.x * wc.x + cv.y * wc.y + cv.z * wc.z + cv.w * wc.w;
      }
    }
    const float x0 = xsel[(b * 128 + tD + 1) * 2], x1 = xsel[(b * 128 + tD + 1) * 2 + 1];
    float gr = ah[0] + bh2[c];
    float gz = ah[1] + bh2[c + 512];
    float gn = ah[2] + bh2[c + 1024];
    float ir = A2[c * 2] * x0 + A2[c * 2 + 1] * x1 + c2[c] + ai[0];
    float iz = A2[(c + 512) * 2] * x0 + A2[(c + 512) * 2 + 1] * x1 + c2[c + 512] + ai[1];
    float in_ = A2[(c + 1024) * 2] * x0 + A2[(c + 1024) * 2 + 1] * x1 + c2[c + 1024] + ai[2];
    float r = sigm(ir + gr), z = sigm(iz + gz);
    float n = tanh_(in_ + r * gn);
    h2n[b * HH + c] = (1.f - z) * n + z * h2p[b * HH + c];
  }
}

// ===========================================================================
// Epilogue: mu/logvar/z from h2(126) (ring slot 126&1 = 0)
// ===========================================================================
__global__ __launch_bounds__(128)
void final_kernel(const float* __restrict__ h2buf, const float* __restrict__ eps,
                  const float* __restrict__ W1, const float* __restrict__ b1,
                  const float* __restrict__ W2, const float* __restrict__ b2,
                  float* __restrict__ out)
{
  const int b = blockIdx.x, t = threadIdx.x;
  __shared__ float hS[512];
  const float* h2 = h2buf + b * HH;      // slot 0
  for (int i = t; i < 512; i += 128) hS[i] = h2[i];
  __syncthreads();
  if (t < OSS) {
    const float* w1 = W1 + (size_t)t * HH;
    const float* w2 = W2 + (size_t)t * HH;
    float mu = b1[t], lv = b2[t];
    for (int kk = 0; kk < 512; ++kk) { float h = hS[kk]; mu += h * w1[kk]; lv += h * w2[kk]; }
    float zz = mu + eps[b * OSS + t] * __expf(0.5f * lv);
    out[b * OSS + t] = zz;
    out[BB * OSS + b * OSS + t] = mu;
    out[2 * BB * OSS + b * OSS + t] = lv;
  }
}

// ===========================================================================
extern "C" void kernel_launch(void* const* d_in, const int* in_sizes, int n_in,
                              void* d_out, int out_size, void* d_ws, size_t ws_size,
                              hipStream_t stream)
{
  const float* instance = (const float*)d_in[0];
  const int*   solution = (const int*)d_in[1];
  const float* Hst      = (const float*)d_in[2];
  const float* eps      = (const float*)d_in[3];
  const float* Wr  = (const float*)d_in[4];
  const float* br  = (const float*)d_in[5];
  const float* Wi1 = (const float*)d_in[6];
  const float* Wh1 = (const float*)d_in[7];
  const float* bi1 = (const float*)d_in[8];
  const float* bh1 = (const float*)d_in[9];
  const float* Wa  = (const float*)d_in[10];
  const float* Ua  = (const float*)d_in[11];
  const float* v   = (const float*)d_in[12];
  const float* Wi2 = (const float*)d_in[13];
  const float* Wh2 = (const float*)d_in[14];
  const float* bi2 = (const float*)d_in[15];
  const float* bh2 = (const float*)d_in[16];
  const float* W1  = (const float*)d_in[17];
  const float* b1  = (const float*)d_in[18];
  const float* W2  = (const float*)d_in[19];
  const float* b2  = (const float*)d_in[20];

  float* wsf   = (float*)d_ws;
  float* P     = wsf;                   // 8,388,608
  float* xsel  = P + 8388608;           // 32,768
  float* A1    = xsel + 32768;          // 3,072
  float* A2    = A1 + 3072;             // 3,072
  float* c1    = A2 + 3072;             // 1,536
  float* c2    = c1 + 1536;             // 1,536
  float* h1buf = c2 + 1536;             // 131,072
  float* h2buf = h1buf + 131072;        // 131,072
  float* ubuf  = h2buf + 131072;        // 131,072
  float* attbuf= ubuf + 131072;         // 266,240
  float* ctxbuf= attbuf + 266240;       // 131,072  -> total 9,221,120 f = 36.9 MB

  prep_kernel<<<dim3(2056), dim3(256), 0, stream>>>(
      instance, solution, Hst, Wr, br, Wi1, bi1, Wi2, bi2, Wa,
      P, xsel, A1, A2, c1, c2, h1buf, h2buf);

  for (int k = 0; k < 131; ++k)
    step_kernel<<<dim3(720), dim3(256), 0, stream>>>(
        k, Hst, Wh1, bh1, Ua, v, Wi2, Wh2, bh2,
        P, xsel, A1, A2, c1, c2, h1buf, h2buf, ubuf, attbuf, ctxbuf);

  final_kernel<<<dim3(128), dim3(128), 0, stream>>>(h2buf, eps, W1, b1, W2, b2, (float*)d_out);
}

// Round 2
// 9454.984 us; speedup vs baseline: 1.3753x; 1.3753x over previous
//
#include <hip/hip_runtime.h>
#include <math.h>

// B=128, S=L=128, H=512, 3H=1536, T=127 steps, SS=100
//
// ws layout (floats):
//   P      [16384][512]   8,388,608   inst_proj rows m=b*128+s
//   WhT1   [512][1536]      786,432   Wh1 transposed (k-major)
//   UaT    [512][512]       262,144
//   WD     [1024][1536]   1,572,864   rows 0-511: Wh2^T ; rows 512-1023: Wi2[:,512:]^T
//   xselT  [256][128]        32,768   xselT[(l*2+d)*128+b] = instance[b, sol[b,l], d]
//   A1f    [1536][2]          3,072   Wi1 @ Wr fold
//   A2f    [1536][2]          3,072   Wi2[:, :512] @ Wr fold
//   c1f    [1536]             1,536   Wi1@br + bi1
//   c2f    [1536]             1,536   Wi2[:,:512]@br + bi2
//   h1T    [2][512][128]    131,072   h1 transposed, ring by t&1
//   vstack [2][1024][128]   262,144   pair slot p: rows 0-511 h2(t-1), 512-1023 ctx(t), p=t&1
//   uT     [2][512][128]    131,072
//   part   [2][4][128][512] 524,288   per-quarter unnormalized context
//   mzbuf  [2][4][128][2]     2,048   per-quarter (max, sumexp)
// total 12,102,656 floats = 46.2 MiB

__device__ __forceinline__ float sigm(float x){ return 1.0f/(1.0f+__expf(-x)); }
__device__ __forceinline__ float tanh_(float x){ float e=__expf(2.0f*x); return 1.0f-2.0f/(e+1.0f); }

// ===========================================================================
// prep: P GEMM (LDS-tiled), weight transposes, input-fold, xselT, zero-init
// grid 2057 x 256
// ===========================================================================
__global__ __launch_bounds__(256)
void prep_kernel(const float* __restrict__ instance, const int* __restrict__ solution,
                 const float* __restrict__ Hst, const float* __restrict__ Wr,
                 const float* __restrict__ br, const float* __restrict__ Wi1,
                 const float* __restrict__ bi1, const float* __restrict__ Wh1,
                 const float* __restrict__ Wa, const float* __restrict__ Ua,
                 const float* __restrict__ Wi2, const float* __restrict__ Wh2,
                 const float* __restrict__ bi2,
                 float* __restrict__ P, float* __restrict__ WhT1, float* __restrict__ UaT,
                 float* __restrict__ WD, float* __restrict__ xselT,
                 float* __restrict__ A1f, float* __restrict__ A2f,
                 float* __restrict__ c1f, float* __restrict__ c2f,
                 float* __restrict__ h1T, float* __restrict__ vstack)
{
  const int w = blockIdx.x, t = threadIdx.x;
  __shared__ float smem[6656];   // P: hS[32][136] (4352) + wS[32][72] (2304); transp: tS[64][65]

  if (w < 1024) {
    // ---- P[m][h] = sum_k Hst[m][k] * Wa[h][k]; tile 128m x 64h, k-tiles of 32
    const int m0 = (w >> 3) * 128, h0 = (w & 7) * 64;
    const int hl = t & 15, mseg = t >> 4;   // thread: 4 h, 8 m
    float acc[4][8];
#pragma unroll
    for (int i = 0; i < 4; ++i)
#pragma unroll
      for (int r = 0; r < 8; ++r) acc[i][r] = 0.f;
    for (int kt = 0; kt < 16; ++kt) {
      { // stage Hst tile transposed: hS[kk][m]
        int row = t >> 1, cb = (t & 1) * 16;
        const float4* sp = (const float4*)(Hst + (size_t)(m0 + row) * 512 + kt * 32 + cb);
        float4 q0 = sp[0], q1 = sp[1], q2 = sp[2], q3 = sp[3];
        float vals[16] = {q0.x,q0.y,q0.z,q0.w,q1.x,q1.y,q1.z,q1.w,
                          q2.x,q2.y,q2.z,q2.w,q3.x,q3.y,q3.z,q3.w};
#pragma unroll
        for (int i = 0; i < 16; ++i) smem[(cb + i) * 136 + row] = vals[i];
      }
      { // stage Wa tile transposed: wS[kk][h]
        int row = t >> 2, cb = (t & 3) * 8;
        const float4* sp = (const float4*)(Wa + (size_t)(h0 + row) * 512 + kt * 32 + cb);
        float4 q0 = sp[0], q1 = sp[1];
        float vals[8] = {q0.x,q0.y,q0.z,q0.w,q1.x,q1.y,q1.z,q1.w};
#pragma unroll
        for (int i = 0; i < 8; ++i) smem[4352 + (cb + i) * 72 + row] = vals[i];
      }
      __syncthreads();
#pragma unroll 8
      for (int kk = 0; kk < 32; ++kk) {
        float4 wv = *(const float4*)&smem[4352 + kk * 72 + hl * 4];
        float4 ha = *(const float4*)&smem[kk * 136 + mseg * 8];
        float4 hb = *(const float4*)&smem[kk * 136 + mseg * 8 + 4];
        float wv_[4] = {wv.x, wv.y, wv.z, wv.w};
        float hv_[8] = {ha.x, ha.y, ha.z, ha.w, hb.x, hb.y, hb.z, hb.w};
#pragma unroll
        for (int i = 0; i < 4; ++i)
#pragma unroll
          for (int r = 0; r < 8; ++r) acc[i][r] += wv_[i] * hv_[r];
      }
      __syncthreads();
    }
#pragma unroll
    for (int r = 0; r < 8; ++r) {
      float4 st = {acc[0][r], acc[1][r], acc[2][r], acc[3][r]};
      *(float4*)&P[(size_t)(m0 + mseg * 8 + r) * 512 + h0 + hl * 4] = st;
    }

  } else if (w < 1664) {
    // ---- transposes via LDS 64x64 tile
    const int wt = w - 1024;
    const float* sp; float* dp; int r0, c0; size_t srs, drs;
    if (wt < 192)      { int q = wt;       sp = Wh1;       dp = WhT1;           r0=(q/8)*64; c0=(q%8)*64; srs=512;  drs=1536; }
    else if (wt < 384) { int q = wt - 192; sp = Wh2;       dp = WD;             r0=(q/8)*64; c0=(q%8)*64; srs=512;  drs=1536; }
    else if (wt < 576) { int q = wt - 384; sp = Wi2 + 512; dp = WD + 512*1536;  r0=(q/8)*64; c0=(q%8)*64; srs=1024; drs=1536; }
    else               { int q = wt - 576; sp = Ua;        dp = UaT;            r0=(q/8)*64; c0=(q%8)*64; srs=512;  drs=512;  }
    int row = t >> 2, cb = (t & 3) * 16;
    const float4* s2 = (const float4*)(sp + (size_t)(r0 + row) * srs + c0 + cb);
    float4 q0 = s2[0], q1 = s2[1], q2 = s2[2], q3 = s2[3];
    float vals[16] = {q0.x,q0.y,q0.z,q0.w,q1.x,q1.y,q1.z,q1.w,
                      q2.x,q2.y,q2.z,q2.w,q3.x,q3.y,q3.z,q3.w};
#pragma unroll
    for (int i = 0; i < 16; ++i) smem[row * 65 + cb + i] = vals[i];
    __syncthreads();
    float* d2 = dp + (size_t)(c0 + row) * drs + r0 + cb;
#pragma unroll
    for (int g = 0; g < 4; ++g) {
      float4 o = {smem[(cb + g*4 + 0) * 65 + row], smem[(cb + g*4 + 1) * 65 + row],
                  smem[(cb + g*4 + 2) * 65 + row], smem[(cb + g*4 + 3) * 65 + row]};
      *(float4*)(d2 + g * 4) = o;
    }

  } else if (w < 2048) {
    // ---- fold: A1f/c1f from Wi1, A2f/c2f from Wi2[:, :512]; one j per wave
    const int wf = w - 1664, wv = t >> 6, lane = t & 63;
    const int j = wf * 4 + wv;
    const float4* w1p = (const float4*)(Wi1 + (size_t)j * 512 + lane * 8);
    const float4* w2p = (const float4*)(Wi2 + (size_t)j * 1024 + lane * 8);
    const float4* wrp = (const float4*)(Wr + lane * 16);
    const float4* brp = (const float4*)(br + lane * 8);
    float4 u0 = w1p[0], u1 = w1p[1], v0 = w2p[0], v1 = w2p[1];
    float4 r0 = wrp[0], r1 = wrp[1], r2 = wrp[2], r3 = wrp[3];
    float4 bb0 = brp[0], bb1 = brp[1];
    float w1a[8] = {u0.x,u0.y,u0.z,u0.w,u1.x,u1.y,u1.z,u1.w};
    float w2a[8] = {v0.x,v0.y,v0.z,v0.w,v1.x,v1.y,v1.z,v1.w};
    float wr0[8] = {r0.x,r0.z,r1.x,r1.z,r2.x,r2.z,r3.x,r3.z};
    float wr1[8] = {r0.y,r0.w,r1.y,r1.w,r2.y,r2.w,r3.y,r3.w};
    float bra[8] = {bb0.x,bb0.y,bb0.z,bb0.w,bb1.x,bb1.y,bb1.z,bb1.w};
    float a0=0,a1=0,cc=0,b0=0,b1=0,cc2=0;
#pragma unroll
    for (int i = 0; i < 8; ++i) {
      a0 += w1a[i]*wr0[i]; a1 += w1a[i]*wr1[i]; cc  += w1a[i]*bra[i];
      b0 += w2a[i]*wr0[i]; b1 += w2a[i]*wr1[i]; cc2 += w2a[i]*bra[i];
    }
#pragma unroll
    for (int off = 32; off; off >>= 1) {
      a0 += __shfl_xor(a0, off); a1 += __shfl_xor(a1, off); cc  += __shfl_xor(cc, off);
      b0 += __shfl_xor(b0, off); b1 += __shfl_xor(b1, off); cc2 += __shfl_xor(cc2, off);
    }
    if (lane == 0) {
      A1f[j*2] = a0; A1f[j*2+1] = a1; c1f[j] = cc + bi1[j];
      A2f[j*2] = b0; A2f[j*2+1] = b1; c2f[j] = cc2 + bi2[j];
    }

  } else if (w == 2048) {
    // ---- xselT[(l*2+d)*128 + b] = instance[b, sol[b,l], d]
    for (int o = t; o < 32768; o += 256) {
      int b = o & 127, r = o >> 7, d = r & 1, l = r >> 1;
      int sel = solution[b * 128 + l];
      xselT[o] = instance[(size_t)(b * 128 + sel) * 2 + d];
    }
  } else {
    // ---- zero h1T slot1 and vstack slot0 rows 0..511 (h states at t=-1)
    const int wz = w - 2049;
    for (int i = 0; i < 32; ++i) {
      int idx = wz * 8192 + i * 256 + t;
      h1T[65536 + idx] = 0.f;
      vstack[idx] = 0.f;
    }
  }
}

// ===========================================================================
// step kernel, software-pipelined: stage k runs A(t=k) U(k-1) B(k-2) C(k-3) D(k-4)
// grid 1184 x 512
// ===========================================================================
__global__ __launch_bounds__(512)
void step_kernel(int k, const float* __restrict__ Hst, const float* __restrict__ bh1,
                 const float* __restrict__ vvec, const float* __restrict__ bh2,
                 const float* __restrict__ P, const float* __restrict__ WhT1,
                 const float* __restrict__ UaT, const float* __restrict__ WD,
                 const float* __restrict__ xselT, const float* __restrict__ A1f,
                 const float* __restrict__ A2f, const float* __restrict__ c1f,
                 const float* __restrict__ c2f,
                 float* __restrict__ h1T, float* __restrict__ vstack,
                 float* __restrict__ uT, float* __restrict__ part,
                 float* __restrict__ mzbuf)
{
  const int w = blockIdx.x, t = threadIdx.x;
  __shared__ float lds[6144];

  if (w < 256) {
    // ---- A: GRU1. gh1 = h1(t-1) @ Wh1^T; c-block 2, k-split 8 waves
    const int tA = k; if (tA > 126) return;
    const int wv = __builtin_amdgcn_readfirstlane(t >> 6);
    const int lane = t & 63;
    const int c0 = w * 2;
    const float* h1p = h1T + ((tA + 1) & 1) * 65536;
    float acc[12];
#pragma unroll
    for (int i = 0; i < 12; ++i) acc[i] = 0.f;
    const float* hrow = h1p + wv * 64 * 128 + lane * 2;
    const float* wrow = WhT1 + (size_t)(wv * 64) * 1536 + c0;
    for (int kk = 0; kk < 64; ++kk) {
      float2 hv = *(const float2*)hrow;
      float w00 = wrow[0],    w01 = wrow[1];
      float w10 = wrow[512],  w11 = wrow[513];
      float w20 = wrow[1024], w21 = wrow[1025];
      acc[0] += hv.x*w00; acc[1] += hv.y*w00; acc[2]  += hv.x*w01; acc[3]  += hv.y*w01;
      acc[4] += hv.x*w10; acc[5] += hv.y*w10; acc[6]  += hv.x*w11; acc[7]  += hv.y*w11;
      acc[8] += hv.x*w20; acc[9] += hv.y*w20; acc[10] += hv.x*w21; acc[11] += hv.y*w21;
      hrow += 128; wrow += 1536;
    }
#pragma unroll
    for (int i = 0; i < 12; ++i) lds[(wv * 12 + i) * 64 + lane] = acc[i];
    __syncthreads();
    if (t < 256) {
      int b = t & 127, ci = t >> 7, ln = b >> 1, bs = b & 1;
      float gr = 0, gz = 0, gn = 0;
#pragma unroll
      for (int w2 = 0; w2 < 8; ++w2) {
        gr += lds[(w2 * 12 +     ci * 2 + bs) * 64 + ln];
        gz += lds[(w2 * 12 + 4 + ci * 2 + bs) * 64 + ln];
        gn += lds[(w2 * 12 + 8 + ci * 2 + bs) * 64 + ln];
      }
      int c = c0 + ci;
      float x0 = xselT[(tA * 2) * 128 + b], x1 = xselT[(tA * 2 + 1) * 128 + b];
      float ir  = A1f[c*2]*x0          + A1f[c*2+1]*x1          + c1f[c];
      float iz  = A1f[(c+512)*2]*x0    + A1f[(c+512)*2+1]*x1    + c1f[c+512];
      float in_ = A1f[(c+1024)*2]*x0   + A1f[(c+1024)*2+1]*x1   + c1f[c+1024];
      float r = sigm(ir + gr + bh1[c]);
      float z = sigm(iz + gz + bh1[c + 512]);
      float n = tanh_(in_ + r * (gn + bh1[c + 1024]));
      float hp = h1p[c * 128 + b];
      h1T[(tA & 1) * 65536 + c * 128 + b] = (1.f - z) * n + z * hp;
    }

  } else if (w < 384) {
    // ---- U: u = h1(t) @ Ua^T; c-block 4, k-split 8
    const int tU = k - 1; if (tU < 0 || tU > 126) return;
    const int wv = __builtin_amdgcn_readfirstlane(t >> 6);
    const int lane = t & 63;
    const int c0 = (w - 256) * 4;
    const float* h1c = h1T + (tU & 1) * 65536;
    float acc[8];
#pragma unroll
    for (int i = 0; i < 8; ++i) acc[i] = 0.f;
    const float* hrow = h1c + wv * 64 * 128 + lane * 2;
    const float* wrow = UaT + (size_t)(wv * 64) * 512 + c0;
    for (int kk = 0; kk < 64; ++kk) {
      float2 hv = *(const float2*)hrow;
      float w0 = wrow[0], w1 = wrow[1], w2 = wrow[2], w3 = wrow[3];
      acc[0] += hv.x*w0; acc[1] += hv.y*w0; acc[2] += hv.x*w1; acc[3] += hv.y*w1;
      acc[4] += hv.x*w2; acc[5] += hv.y*w2; acc[6] += hv.x*w3; acc[7] += hv.y*w3;
      hrow += 128; wrow += 512;
    }
#pragma unroll
    for (int i = 0; i < 8; ++i) lds[(wv * 8 + i) * 64 + lane] = acc[i];
    __syncthreads();
    {
      int b = t & 127, q = t >> 7;
      float u = 0;
#pragma unroll
      for (int w2 = 0; w2 < 8; ++w2) u += lds[(w2 * 8 + q * 2 + (b & 1)) * 64 + (b >> 1)];
      uT[(tU & 1) * 65536 + (c0 + q) * 128 + b] = u;
    }

  } else if (w < 896) {
    // ---- B: additive attention, one (b, s-quarter) per WG
    const int tB = k - 2; if (tB < 0 || tB > 126) return;
    const int wb = w - 384, b = wb >> 2, q = wb & 3;
    const int slot = tB & 1;
    float* uS = lds, *vS = lds + 512, *scS = lds + 1024, *wgt = lds + 1056;
    uS[t] = uT[slot * 65536 + t * 128 + b];
    vS[t] = vvec[t];
    __syncthreads();
    const int wv8 = t >> 6, lane = t & 63, h0 = lane * 8;
#pragma unroll
    for (int si = 0; si < 4; ++si) {
      int s = q * 32 + wv8 * 4 + si;
      const float* prow = P + (size_t)(b * 128 + s) * 512 + h0;
      float4 p0 = ((const float4*)prow)[0];
      float4 p1 = ((const float4*)prow)[1];
      float val = tanh_(p0.x + uS[h0+0]) * vS[h0+0]
                + tanh_(p0.y + uS[h0+1]) * vS[h0+1]
                + tanh_(p0.z + uS[h0+2]) * vS[h0+2]
                + tanh_(p0.w + uS[h0+3]) * vS[h0+3]
                + tanh_(p1.x + uS[h0+4]) * vS[h0+4]
                + tanh_(p1.y + uS[h0+5]) * vS[h0+5]
                + tanh_(p1.z + uS[h0+6]) * vS[h0+6]
                + tanh_(p1.w + uS[h0+7]) * vS[h0+7];
#pragma unroll
      for (int off = 32; off; off >>= 1) val += __shfl_xor(val, off);
      if (lane == 0) scS[wv8 * 4 + si] = val;
    }
    __syncthreads();
    if (t < 32) {
      float sc = scS[t], m = sc;
#pragma unroll
      for (int off = 16; off; off >>= 1) m = fmaxf(m, __shfl_xor(m, off));
      float e = __expf(sc - m);
      float zz = e;
#pragma unroll
      for (int off = 16; off; off >>= 1) zz += __shfl_xor(zz, off);
      wgt[t] = e;
      if (t == 0) {
        int mzi = ((slot * 4 + q) * 128 + b) * 2;
        mzbuf[mzi] = m; mzbuf[mzi + 1] = zz;
      }
    }
    __syncthreads();
    float a = 0.f;
    const float* hb = Hst + (size_t)(b * 128 + q * 32) * 512 + t;
#pragma unroll 8
    for (int s = 0; s < 32; ++s) a += wgt[s] * hb[(size_t)s * 512];
    part[((size_t)(slot * 4 + q) * 128 + b) * 512 + t] = a;

  } else if (w < 928) {
    // ---- C: combine quarters -> ctxT rows of vstack[slot]
    const int tC = k - 3; if (tC < 0 || tC > 126) return;
    const int slot = tC & 1;
    float* scale = lds;
    if (t < 128) {
      int b = t;
      float m0 = mzbuf[((slot*4+0)*128+b)*2], z0 = mzbuf[((slot*4+0)*128+b)*2+1];
      float m1 = mzbuf[((slot*4+1)*128+b)*2], z1 = mzbuf[((slot*4+1)*128+b)*2+1];
      float m2 = mzbuf[((slot*4+2)*128+b)*2], z2 = mzbuf[((slot*4+2)*128+b)*2+1];
      float m3 = mzbuf[((slot*4+3)*128+b)*2], z3 = mzbuf[((slot*4+3)*128+b)*2+1];
      float M = fmaxf(fmaxf(m0, m1), fmaxf(m2, m3));
      float e0 = __expf(m0 - M), e1 = __expf(m1 - M), e2 = __expf(m2 - M), e3 = __expf(m3 - M);
      float inv = 1.f / (z0*e0 + z1*e1 + z2*e2 + z3*e3);
      scale[b] = e0*inv; scale[128+b] = e1*inv; scale[256+b] = e2*inv; scale[384+b] = e3*inv;
    }
    __syncthreads();
    const int base = (w - 896) * 2048;
#pragma unroll
    for (int i = 0; i < 4; ++i) {
      int o = base + i * 512 + t;
      int b = o & 127, kk = o >> 7;
      float vsum = scale[b]       * part[((size_t)(slot*4+0)*128 + b)*512 + kk]
                 + scale[128 + b] * part[((size_t)(slot*4+1)*128 + b)*512 + kk]
                 + scale[256 + b] * part[((size_t)(slot*4+2)*128 + b)*512 + kk]
                 + scale[384 + b] * part[((size_t)(slot*4+3)*128 + b)*512 + kk];
      vstack[slot * 131072 + (512 + kk) * 128 + b] = vsum;
    }

  } else {
    // ---- D: GRU2 over stacked [h2(t-1); ctx(t)] K=1024; c-block 2, k-split 8
    const int tD = k - 4; if (tD < 0 || tD > 126) return;
    const int wv = __builtin_amdgcn_readfirstlane(t >> 6);
    const int lane = t & 63;
    const int c0 = (w - 928) * 2;
    const int pair = tD & 1;
    const float* vs = vstack + pair * 131072;
    float acc[12];
#pragma unroll
    for (int i = 0; i < 12; ++i) acc[i] = 0.f;
    const float* hrow = vs + wv * 128 * 128 + lane * 2;
    const float* wrow = WD + (size_t)(wv * 128) * 1536 + c0;
    for (int kk = 0; kk < 128; ++kk) {
      float2 hv = *(const float2*)hrow;
      float w00 = wrow[0],    w01 = wrow[1];
      float w10 = wrow[512],  w11 = wrow[513];
      float w20 = wrow[1024], w21 = wrow[1025];
      acc[0] += hv.x*w00; acc[1] += hv.y*w00; acc[2]  += hv.x*w01; acc[3]  += hv.y*w01;
      acc[4] += hv.x*w10; acc[5] += hv.y*w10; acc[6]  += hv.x*w11; acc[7]  += hv.y*w11;
      acc[8] += hv.x*w20; acc[9] += hv.y*w20; acc[10] += hv.x*w21; acc[11] += hv.y*w21;
      hrow += 128; wrow += 1536;
    }
#pragma unroll
    for (int i = 0; i < 12; ++i) lds[(wv * 12 + i) * 64 + lane] = acc[i];
    __syncthreads();
    if (t < 256) {
      int b = t & 127, ci = t >> 7, ln = b >> 1, bs = b & 1;
      float gr = 0, gz = 0, gnh = 0, gni = 0;
#pragma unroll
      for (int w2 = 0; w2 < 8; ++w2) {
        gr += lds[(w2 * 12 +     ci * 2 + bs) * 64 + ln];
        gz += lds[(w2 * 12 + 4 + ci * 2 + bs) * 64 + ln];
        float g = lds[(w2 * 12 + 8 + ci * 2 + bs) * 64 + ln];
        if (w2 < 4) gnh += g; else gni += g;   // hidden part vs ctx (input) part of n-gate
      }
      int c = c0 + ci;
      float x0 = xselT[((tD + 1) * 2) * 128 + b], x1 = xselT[((tD + 1) * 2 + 1) * 128 + b];
      float ir  = A2f[c*2]*x0        + A2f[c*2+1]*x1        + c2f[c];
      float iz  = A2f[(c+512)*2]*x0  + A2f[(c+512)*2+1]*x1  + c2f[c+512];
      float in_ = A2f[(c+1024)*2]*x0 + A2f[(c+1024)*2+1]*x1 + c2f[c+1024] + gni;
      float r = sigm(ir + gr + bh2[c]);
      float z = sigm(iz + gz + bh2[c + 512]);
      float n = tanh_(in_ + r * (gnh + bh2[c + 1024]));
      float hp = vs[c * 128 + b];
      vstack[((tD + 1) & 1) * 131072 + c * 128 + b] = (1.f - z) * n + z * hp;
    }
  }
}

// ===========================================================================
// epilogue: mu/logvar/z from h2(126) (vstack slot 1, rows 0..511)
// ===========================================================================
__global__ __launch_bounds__(128)
void final_kernel(const float* __restrict__ vstack, const float* __restrict__ eps,
                  const float* __restrict__ W1, const float* __restrict__ b1,
                  const float* __restrict__ W2, const float* __restrict__ b2,
                  float* __restrict__ out)
{
  const int b = blockIdx.x, t = threadIdx.x;
  __shared__ float hS[512];
  const float* h2 = vstack + 131072;
  for (int i = t; i < 512; i += 128) hS[i] = h2[i * 128 + b];
  __syncthreads();
  if (t < 100) {
    const float* w1 = W1 + (size_t)t * 512;
    const float* w2 = W2 + (size_t)t * 512;
    float mu = b1[t], lv = b2[t];
    for (int kk = 0; kk < 512; ++kk) { float h = hS[kk]; mu += h * w1[kk]; lv += h * w2[kk]; }
    float zz = mu + eps[b * 100 + t] * __expf(0.5f * lv);
    out[b * 100 + t] = zz;
    out[12800 + b * 100 + t] = mu;
    out[25600 + b * 100 + t] = lv;
  }
}

// ===========================================================================
extern "C" void kernel_launch(void* const* d_in, const int* in_sizes, int n_in,
                              void* d_out, int out_size, void* d_ws, size_t ws_size,
                              hipStream_t stream)
{
  const float* instance = (const float*)d_in[0];
  const int*   solution = (const int*)d_in[1];
  const float* Hst      = (const float*)d_in[2];
  const float* eps      = (const float*)d_in[3];
  const float* Wr  = (const float*)d_in[4];
  const float* br  = (const float*)d_in[5];
  const float* Wi1 = (const float*)d_in[6];
  const float* Wh1 = (const float*)d_in[7];
  const float* bi1 = (const float*)d_in[8];
  const float* bh1 = (const float*)d_in[9];
  const float* Wa  = (const float*)d_in[10];
  const float* Ua  = (const float*)d_in[11];
  const float* v   = (const float*)d_in[12];
  const float* Wi2 = (const float*)d_in[13];
  const float* Wh2 = (const float*)d_in[14];
  const float* bi2 = (const float*)d_in[15];
  const float* bh2 = (const float*)d_in[16];
  const float* W1  = (const float*)d_in[17];
  const float* b1  = (const float*)d_in[18];
  const float* W2  = (const float*)d_in[19];
  const float* b2  = (const float*)d_in[20];

  float* wsf   = (float*)d_ws;
  float* P     = wsf;                    // 8,388,608
  float* WhT1  = P     + 8388608;        //   786,432
  float* UaT   = WhT1  + 786432;         //   262,144
  float* WD    = UaT   + 262144;         // 1,572,864
  float* xselT = WD    + 1572864;        //    32,768
  float* A1f   = xselT + 32768;          //     3,072
  float* A2f   = A1f   + 3072;           //     3,072
  float* c1f   = A2f   + 3072;           //     1,536
  float* c2f   = c1f   + 1536;           //     1,536
  float* h1T   = c2f   + 1536;           //   131,072
  float* vstack= h1T   + 131072;         //   262,144
  float* uT    = vstack+ 262144;         //   131,072
  float* part  = uT    + 131072;         //   524,288
  float* mzbuf = part  + 524288;         //     2,048

  prep_kernel<<<dim3(2057), dim3(256), 0, stream>>>(
      instance, solution, Hst, Wr, br, Wi1, bi1, Wh1, Wa, Ua, Wi2, Wh2, bi2,
      P, WhT1, UaT, WD, xselT, A1f, A2f, c1f, c2f, h1T, vstack);

  for (int k = 0; k < 131; ++k)
    step_kernel<<<dim3(1184), dim3(512), 0, stream>>>(
        k, Hst, bh1, v, bh2, P, WhT1, UaT, WD, xselT, A1f, A2f, c1f, c2f,
        h1T, vstack, uT, part, mzbuf);

  final_kernel<<<dim3(128), dim3(128), 0, stream>>>(vstack, eps, W1, b1, W2, b2, (float*)d_out);
}